// Round 6
// baseline (398.436 us; speedup 1.0000x reference)
//
#include <hip/hip_runtime.h>

// ---------------- problem constants ----------------
static constexpr int N_NODES = 100000;
static constexpr int N_EDGES = 3200000;
static constexpr int SHIFT  = 8;                          // 256 nodes / bucket
static constexpr int NPB    = 1 << SHIFT;                 // 256
static constexpr int NBK    = (N_NODES + NPB - 1) / NPB;  // 391 buckets
static constexpr int WGC    = 1280;                       // partition workgroups (mult of 64 for prefix)
static constexpr int CHUNK  = N_EDGES / WGC;              // 2500 edges / WG (exact)

// ---------------- bf16 helpers ----------------
__device__ __forceinline__ unsigned bf16rne(float f) {
    unsigned u = __float_as_uint(f);
    u += 0x7fffu + ((u >> 16) & 1u);
    return u >> 16;
}
__device__ __forceinline__ unsigned pack2(float lo, float hi) {
    return bf16rne(lo) | (bf16rne(hi) << 16);
}

// ---- K1: per-WG histograms for both keys; transposed count matrices [NBK][WGC]
__global__ void __launch_bounds__(256) k_count(
    const int* __restrict__ row, const int* __restrict__ col,
    unsigned* __restrict__ cmC, unsigned* __restrict__ cmR)
{
    __shared__ unsigned hC[NBK], hR[NBK];
    for (int b = threadIdx.x; b < NBK; b += 256) { hC[b] = 0u; hR[b] = 0u; }
    __syncthreads();
    int w = blockIdx.x, e0 = w * CHUNK;
    for (int e = e0 + threadIdx.x; e < e0 + CHUNK; e += 256) {
        atomicAdd(&hC[col[e] >> SHIFT], 1u);
        atomicAdd(&hR[row[e] >> SHIFT], 1u);
    }
    __syncthreads();
    for (int b = threadIdx.x; b < NBK; b += 256) {
        cmC[(size_t)b * WGC + w] = hC[b];
        cmR[(size_t)b * WGC + w] = hR[b];
    }
}

// ---- K2: exclusive prefix over WGs per bucket (one warp per bucket row)
__global__ void __launch_bounds__(256) k_prefix(
    unsigned* __restrict__ cmC, unsigned* __restrict__ cmR,
    unsigned* __restrict__ totC, unsigned* __restrict__ totR)
{
    int warp = (blockIdx.x * 256 + threadIdx.x) >> 6;
    int lane = threadIdx.x & 63;
    if (warp >= 2 * NBK) return;
    unsigned* cm  = (warp < NBK) ? cmC : cmR;
    unsigned* tot = (warp < NBK) ? totC : totR;
    int b = (warp < NBK) ? warp : warp - NBK;
    unsigned* rowp = cm + (size_t)b * WGC;
    unsigned carry = 0;
    for (int base = 0; base < WGC; base += 64) {
        unsigned v = rowp[base + lane];
        unsigned inc = v;
        for (int off = 1; off < 64; off <<= 1) {
            unsigned t = __shfl_up(inc, off, 64);
            if (lane >= off) inc += t;
        }
        rowp[base + lane] = carry + inc - v;     // exclusive
        carry += __shfl(inc, 63, 64);
    }
    if (lane == 0) tot[b] = carry;
}

// ---- K3: exclusive scan of bucket totals -> bucket bases (blockIdx 0: col, 1: row)
__global__ void __launch_bounds__(256) k_scan(
    const unsigned* __restrict__ totC, const unsigned* __restrict__ totR,
    unsigned* __restrict__ baseC, unsigned* __restrict__ baseR)
{
    const unsigned* tot = blockIdx.x ? totR : totC;
    unsigned* base = blockIdx.x ? baseR : baseC;
    __shared__ unsigned tsum[256];
    int tid = threadIdx.x;
    unsigned a0 = (2 * tid     < NBK) ? tot[2 * tid]     : 0u;
    unsigned a1 = (2 * tid + 1 < NBK) ? tot[2 * tid + 1] : 0u;
    tsum[tid] = a0 + a1;
    __syncthreads();
    for (int off = 1; off < 256; off <<= 1) {
        unsigned v = (tid >= off) ? tsum[tid - off] : 0u;
        __syncthreads();
        tsum[tid] += v;
        __syncthreads();
    }
    unsigned ex = tid ? tsum[tid - 1] : 0u;
    if (2 * tid     < NBK) base[2 * tid]     = ex;
    if (2 * tid + 1 < NBK) base[2 * tid + 1] = ex + a0;
}

// ---- K4: partition+compute. Streams boo COALESCED, computes bf16x4 message,
//      LDS-stages records, writes bucket-sorted runs coalesced. No global atomics.
template<int TRANS>
__global__ void __launch_bounds__(256) k_partition_msg(
    const int* __restrict__ key,       // destination index (col p1 / row p2)
    const int* __restrict__ pay,       // source index      (row p1 / col p2)
    const float4* __restrict__ vin,    // x (p1) or lt (p2) — L2-resident gather
    const float4* __restrict__ boo,
    const unsigned* __restrict__ cm,   // prefix'd count matrix [NBK][WGC]
    const unsigned* __restrict__ base, // bucket bases [NBK]
    uint2* __restrict__ msgbuf, unsigned char* __restrict__ tagbuf)
{
    __shared__ int      karr[CHUNK];        // 10 KB: keys cached for 2nd loop
    __shared__ uint2    smsg[CHUNK];        // 20 KB: staged messages
    __shared__ unsigned char stag[CHUNK];   // 2.5 KB: staged tags
    __shared__ unsigned hist[NBK];          // counts, then cursors
    __shared__ unsigned runstart[NBK + 1];
    __shared__ unsigned gdst[NBK];
    __shared__ unsigned tsum[256];
    int w = blockIdx.x, tid = threadIdx.x, e0 = w * CHUNK;

    for (int b = tid; b < NBK; b += 256) {
        hist[b] = 0u;
        gdst[b] = base[b] + cm[(size_t)b * WGC + w];
    }
    __syncthreads();
    for (int l = tid; l < CHUNK; l += 256) {
        int k = key[e0 + l];
        karr[l] = k;
        atomicAdd(&hist[k >> SHIFT], 1u);
    }
    __syncthreads();
    // block exclusive scan of hist -> runstart (+ sentinel)
    unsigned a0 = (2 * tid     < NBK) ? hist[2 * tid]     : 0u;
    unsigned a1 = (2 * tid + 1 < NBK) ? hist[2 * tid + 1] : 0u;
    tsum[tid] = a0 + a1;
    __syncthreads();
    for (int off = 1; off < 256; off <<= 1) {
        unsigned v = (tid >= off) ? tsum[tid - off] : 0u;
        __syncthreads();
        tsum[tid] += v;
        __syncthreads();
    }
    unsigned ex = tid ? tsum[tid - 1] : 0u;
    if (2 * tid     <= NBK) runstart[2 * tid]     = ex;
    if (2 * tid + 1 <= NBK) runstart[2 * tid + 1] = ex + a0;
    __syncthreads();
    for (int b = tid; b < NBK; b += 256) hist[b] = runstart[b];  // cursors
    __syncthreads();

    // compute + stage
    for (int l = tid; l < CHUNK; l += 256) {
        int e = e0 + l;
        int k = karr[l];
        int p = pay[e];
        int b = k >> SHIFT;
        float4 v  = vin[p];
        float4 q0 = boo[(size_t)e * 4 + 0];
        float4 q1 = boo[(size_t)e * 4 + 1];
        float4 q2 = boo[(size_t)e * 4 + 2];
        float4 q3 = boo[(size_t)e * 4 + 3];
        float m0, m1, m2, m3;
        if (TRANS) {  // A^T v
            m0 = q0.x * v.x + q1.x * v.y + q2.x * v.z + q3.x * v.w;
            m1 = q0.y * v.x + q1.y * v.y + q2.y * v.z + q3.y * v.w;
            m2 = q0.z * v.x + q1.z * v.y + q2.z * v.z + q3.z * v.w;
            m3 = q0.w * v.x + q1.w * v.y + q2.w * v.z + q3.w * v.w;
        } else {      // A v
            m0 = q0.x * v.x + q0.y * v.y + q0.z * v.z + q0.w * v.w;
            m1 = q1.x * v.x + q1.y * v.y + q1.z * v.z + q1.w * v.w;
            m2 = q2.x * v.x + q2.y * v.y + q2.z * v.z + q2.w * v.w;
            m3 = q3.x * v.x + q3.y * v.y + q3.z * v.z + q3.w * v.w;
        }
        unsigned pos = atomicAdd(&hist[b], 1u);
        smsg[pos] = make_uint2(pack2(m0, m1), pack2(m2, m3));
        stag[pos] = (unsigned char)(k & (NPB - 1));
    }
    __syncthreads();

    // coalesced write-out: bucket of slot s via binary search over runstart
    for (int s = tid; s < CHUNK; s += 256) {
        int lo = 0, hi = NBK;
        while (hi - lo > 1) {
            int mid = (lo + hi) >> 1;
            if (runstart[mid] <= (unsigned)s) lo = mid; else hi = mid;
        }
        size_t g = (size_t)gdst[lo] + (unsigned)s - runstart[lo];
        msgbuf[g] = smsg[s];
        tagbuf[g] = stag[s];
    }
}

// ---- K5: one WG per bucket: stream its message run, f32 LDS accumulate, store
__global__ void __launch_bounds__(512) k_reduce_msg(
    const uint2* __restrict__ msgbuf, const unsigned char* __restrict__ tagbuf,
    const unsigned* __restrict__ base, const unsigned* __restrict__ tot,
    float4* __restrict__ vout)
{
    __shared__ float acc[4][NPB];
    int b = blockIdx.x, tid = threadIdx.x;
    for (int i = tid; i < 4 * NPB; i += 512) ((float*)acc)[i] = 0.f;
    __syncthreads();
    unsigned start = base[b], n = tot[b];
    for (unsigned i = start + tid; i < start + n; i += 512) {
        uint2 m = msgbuf[i];
        int loc = tagbuf[i];
        atomicAdd(&acc[0][loc], __uint_as_float(m.x << 16));
        atomicAdd(&acc[1][loc], __uint_as_float(m.x & 0xffff0000u));
        atomicAdd(&acc[2][loc], __uint_as_float(m.y << 16));
        atomicAdd(&acc[3][loc], __uint_as_float(m.y & 0xffff0000u));
    }
    __syncthreads();
    for (int i = tid; i < NPB; i += 512) {
        int node = b * NPB + i;
        if (node < N_NODES)
            vout[node] = make_float4(acc[0][i], acc[1][i], acc[2][i], acc[3][i]);
    }
}

// ================= fallback path (R3: sector-merged global atomics) =================

__global__ void __launch_bounds__(256) llt_pass1(
    const float* __restrict__ x, const int* __restrict__ row_idx,
    const int* __restrict__ col_idx, const float* __restrict__ boo,
    float* __restrict__ lt)
{
    int t = blockIdx.x * blockDim.x + threadIdx.x;
    if (t >= N_EDGES * 4) return;
    int e = t >> 2, i = t & 3;
    int r = row_idx[e], c = col_idx[e];
    const float* A = boo + (size_t)e * 16;
    const float* xv = x + (size_t)r * 4;
    float m = A[0*4+i]*xv[0] + A[1*4+i]*xv[1] + A[2*4+i]*xv[2] + A[3*4+i]*xv[3];
    atomicAdd(lt + (size_t)c * 4 + i, m);
}

__global__ void __launch_bounds__(256) llt_pass2(
    const float4* __restrict__ lt, const int* __restrict__ row_idx,
    const int* __restrict__ col_idx, const float4* __restrict__ boo,
    float* __restrict__ out)
{
    int t = blockIdx.x * blockDim.x + threadIdx.x;
    if (t >= N_EDGES * 4) return;
    int e = t >> 2, i = t & 3;
    int r = row_idx[e], c = col_idx[e];
    float4 arow = boo[(size_t)e * 4 + i];
    float4 lv = lt[c];
    float m = arow.x*lv.x + arow.y*lv.y + arow.z*lv.z + arow.w*lv.w;
    atomicAdd(out + (size_t)r * 4 + i, m);
}

// ================= host =================

extern "C" void kernel_launch(void* const* d_in, const int* in_sizes, int n_in,
                              void* d_out, int out_size, void* d_ws, size_t ws_size,
                              hipStream_t stream) {
    const float4* x = (const float4*)d_in[0];        // [100000,4] f32
    const int* edge_index = (const int*)d_in[1];     // [2, 3200000] int32
    const float4* boo = (const float4*)d_in[2];      // [3200000,4,4] f32
    const int* row = edge_index;                     // edge_index[0]
    const int* col = edge_index + N_EDGES;           // edge_index[1]
    float4* out = (float4*)d_out;

    auto align256 = [](size_t v) { return (v + 255) & ~(size_t)255; };
    const size_t sz_cm   = align256((size_t)NBK * WGC * 4);   // 2.0 MB each
    const size_t sz_vec  = align256((size_t)NBK * 4);
    const size_t sz_msg  = align256((size_t)N_EDGES * 8);     // 25.6 MB (reused)
    const size_t sz_tag  = align256((size_t)N_EDGES);         // 3.2 MB (reused)
    const size_t sz_lt   = align256((size_t)NBK * NPB * 16);  // 1.6 MB
    const size_t need = 2 * sz_cm + 4 * sz_vec + sz_msg + sz_tag + sz_lt;

    if (ws_size >= need) {
        char* p = (char*)d_ws;
        unsigned* cmC   = (unsigned*)p; p += sz_cm;
        unsigned* cmR   = (unsigned*)p; p += sz_cm;
        unsigned* totC  = (unsigned*)p; p += sz_vec;
        unsigned* totR  = (unsigned*)p; p += sz_vec;
        unsigned* baseC = (unsigned*)p; p += sz_vec;
        unsigned* baseR = (unsigned*)p; p += sz_vec;
        uint2*    msg   = (uint2*)p;    p += sz_msg;
        unsigned char* tag = (unsigned char*)p; p += sz_tag;
        float4*   lt    = (float4*)p;   p += sz_lt;

        k_count<<<WGC, 256, 0, stream>>>(row, col, cmC, cmR);
        k_prefix<<<(2 * NBK + 3) / 4, 256, 0, stream>>>(cmC, cmR, totC, totR);
        k_scan<<<2, 256, 0, stream>>>(totC, totR, baseC, baseR);
        // pass 1: bucket by col, message = A^T x[row]
        k_partition_msg<1><<<WGC, 256, 0, stream>>>(col, row, x, boo, cmC, baseC, msg, tag);
        k_reduce_msg<<<NBK, 512, 0, stream>>>(msg, tag, baseC, totC, lt);
        // pass 2: bucket by row, message = A lt[col]  (msg/tag buffers reused)
        k_partition_msg<0><<<WGC, 256, 0, stream>>>(row, col, (const float4*)lt, boo, cmR, baseR, msg, tag);
        k_reduce_msg<<<NBK, 512, 0, stream>>>(msg, tag, baseR, totR, out);
    } else {
        // fallback: sector-merged atomics (R3, 328 us)
        float* ltf = (float*)d_ws;
        hipMemsetAsync(ltf, 0, (size_t)N_NODES * 4 * sizeof(float), stream);
        hipMemsetAsync(out, 0, (size_t)N_NODES * 4 * sizeof(float), stream);
        const int grid = (N_EDGES * 4 + 255) / 256;
        llt_pass1<<<grid, 256, 0, stream>>>((const float*)x, row, col, (const float*)boo, ltf);
        llt_pass2<<<grid, 256, 0, stream>>>((const float4*)ltf, row, col, boo, (float*)out);
    }
}

// Round 7
// 259.491 us; speedup vs baseline: 1.5355x; 1.5355x over previous
//
#include <hip/hip_runtime.h>

// ---------------- problem constants ----------------
static constexpr int N_NODES = 100000;
static constexpr int N_EDGES = 3200000;
static constexpr int SHIFT  = 8;                          // 256 nodes / bucket
static constexpr int NPB    = 1 << SHIFT;                 // 256
static constexpr int NBK    = (N_NODES + NPB - 1) / NPB;  // 391 buckets
static constexpr int WGC    = 1024;                       // partition workgroups
static constexpr int CHUNK  = N_EDGES / WGC;              // 3125 edges / WG (exact)
static constexpr int PSPLIT = 4;                          // WGs per bucket in reduce

// record: .x = edge id, .y = src | (loc << 17)  (src < 2^17, loc < 256)

// ---- K1: per-WG histograms for both keys; transposed count matrices [NBK][WGC]
__global__ void __launch_bounds__(256) k_count(
    const int* __restrict__ row, const int* __restrict__ col,
    unsigned* __restrict__ cmC, unsigned* __restrict__ cmR)
{
    __shared__ unsigned hC[NBK], hR[NBK];
    for (int b = threadIdx.x; b < NBK; b += 256) { hC[b] = 0u; hR[b] = 0u; }
    __syncthreads();
    int w = blockIdx.x, e0 = w * CHUNK;
    for (int e = e0 + threadIdx.x; e < e0 + CHUNK; e += 256) {
        atomicAdd(&hC[col[e] >> SHIFT], 1u);
        atomicAdd(&hR[row[e] >> SHIFT], 1u);
    }
    __syncthreads();
    for (int b = threadIdx.x; b < NBK; b += 256) {
        cmC[(size_t)b * WGC + w] = hC[b];
        cmR[(size_t)b * WGC + w] = hR[b];
    }
}

// ---- K2: exclusive prefix over WGs per bucket (one warp per bucket row)
__global__ void __launch_bounds__(256) k_prefix(
    unsigned* __restrict__ cmC, unsigned* __restrict__ cmR,
    unsigned* __restrict__ totC, unsigned* __restrict__ totR)
{
    int warp = (blockIdx.x * 256 + threadIdx.x) >> 6;
    int lane = threadIdx.x & 63;
    if (warp >= 2 * NBK) return;
    unsigned* cm  = (warp < NBK) ? cmC : cmR;
    unsigned* tot = (warp < NBK) ? totC : totR;
    int b = (warp < NBK) ? warp : warp - NBK;
    unsigned* rowp = cm + (size_t)b * WGC;
    unsigned carry = 0;
    for (int base = 0; base < WGC; base += 64) {
        unsigned v = rowp[base + lane];
        unsigned inc = v;
        for (int off = 1; off < 64; off <<= 1) {
            unsigned t = __shfl_up(inc, off, 64);
            if (lane >= off) inc += t;
        }
        rowp[base + lane] = carry + inc - v;     // exclusive
        carry += __shfl(inc, 63, 64);
    }
    if (lane == 0) tot[b] = carry;
}

// ---- K3: exclusive scan of bucket totals -> bucket bases (blockIdx 0: col, 1: row)
__global__ void __launch_bounds__(256) k_scan(
    const unsigned* __restrict__ totC, const unsigned* __restrict__ totR,
    unsigned* __restrict__ baseC, unsigned* __restrict__ baseR)
{
    const unsigned* tot = blockIdx.x ? totR : totC;
    unsigned* base = blockIdx.x ? baseR : baseC;
    __shared__ unsigned tsum[256];
    int tid = threadIdx.x;
    unsigned a0 = (2 * tid     < NBK) ? tot[2 * tid]     : 0u;
    unsigned a1 = (2 * tid + 1 < NBK) ? tot[2 * tid + 1] : 0u;
    tsum[tid] = a0 + a1;
    __syncthreads();
    for (int off = 1; off < 256; off <<= 1) {
        unsigned v = (tid >= off) ? tsum[tid - off] : 0u;
        __syncthreads();
        tsum[tid] += v;
        __syncthreads();
    }
    unsigned ex = tid ? tsum[tid - 1] : 0u;
    if (2 * tid     < NBK) base[2 * tid]     = ex;
    if (2 * tid + 1 < NBK) base[2 * tid + 1] = ex + a0;
}

// ---- K4: partition edges into bucket-sorted records, LDS-staged coalesced writes
__global__ void __launch_bounds__(256) k_partition(
    const int* __restrict__ key,       // destination index per edge (col p1 / row p2)
    const int* __restrict__ pay,       // source index per edge      (row p1 / col p2)
    const unsigned* __restrict__ cm,   // prefix'd count matrix [NBK][WGC]
    const unsigned* __restrict__ base, // bucket bases [NBK]
    uint2* __restrict__ perm)
{
    __shared__ unsigned hist[NBK];
    __shared__ unsigned runstart[NBK + 1];
    __shared__ unsigned gdst[NBK];
    __shared__ unsigned tsum[256];
    __shared__ uint2 stage[CHUNK];          // 25 KB
    int w = blockIdx.x, tid = threadIdx.x, e0 = w * CHUNK;

    for (int b = tid; b < NBK; b += 256) {
        hist[b] = 0u;
        gdst[b] = base[b] + cm[(size_t)b * WGC + w];
    }
    __syncthreads();
    for (int e = e0 + tid; e < e0 + CHUNK; e += 256)
        atomicAdd(&hist[key[e] >> SHIFT], 1u);
    __syncthreads();
    unsigned a0 = (2 * tid     < NBK) ? hist[2 * tid]     : 0u;
    unsigned a1 = (2 * tid + 1 < NBK) ? hist[2 * tid + 1] : 0u;
    tsum[tid] = a0 + a1;
    __syncthreads();
    for (int off = 1; off < 256; off <<= 1) {
        unsigned v = (tid >= off) ? tsum[tid - off] : 0u;
        __syncthreads();
        tsum[tid] += v;
        __syncthreads();
    }
    unsigned ex = tid ? tsum[tid - 1] : 0u;
    if (2 * tid     <= NBK) runstart[2 * tid]     = ex;
    if (2 * tid + 1 <= NBK) runstart[2 * tid + 1] = ex + a0;
    __syncthreads();
    for (int b = tid; b < NBK; b += 256) hist[b] = runstart[b];
    __syncthreads();
    for (int e = e0 + tid; e < e0 + CHUNK; e += 256) {
        int k = key[e], p = pay[e];
        int b = k >> SHIFT;
        unsigned pos = atomicAdd(&hist[b], 1u);
        stage[pos] = make_uint2((unsigned)e,
                                (unsigned)p | ((unsigned)(k & (NPB - 1)) << 17));
    }
    __syncthreads();
    for (int s = tid; s < CHUNK; s += 256) {
        int lo = 0, hi = NBK;
        while (hi - lo > 1) {
            int mid = (lo + hi) >> 1;
            if (runstart[mid] <= (unsigned)s) lo = mid; else hi = mid;
        }
        perm[(size_t)gdst[lo] + (unsigned)s - runstart[lo]] = stage[s];
    }
}

// ---- K5: PSPLIT WGs per bucket: gather boo (64B lines) + vin (L2-resident),
//      partial f32 LDS accumulate, merge via sector-merged global f32 atomics.
template<int TRANS>
__global__ void __launch_bounds__(512) k_reduce(
    const uint2* __restrict__ perm,
    const float4* __restrict__ vin,     // x (pass1) or lt (pass2)
    const float4* __restrict__ boo,
    const unsigned* __restrict__ base, const unsigned* __restrict__ tot,
    float* __restrict__ vout)           // pre-zeroed, accumulated atomically
{
    __shared__ float acc[4][NPB];
    int b = blockIdx.x / PSPLIT, sub = blockIdx.x % PSPLIT;
    int tid = threadIdx.x;
    for (int i = tid; i < 4 * NPB; i += 512) ((float*)acc)[i] = 0.f;
    __syncthreads();
    unsigned start = base[b], n = tot[b];
    for (unsigned i = start + sub * 512 + tid; i < start + n; i += 512 * PSPLIT) {
        uint2 rec = perm[i];
        unsigned e   = rec.x;
        unsigned src = rec.y & 0x1FFFFu;
        unsigned loc = rec.y >> 17;
        float4 v  = vin[src];
        float4 a0 = boo[(size_t)e * 4 + 0];
        float4 a1 = boo[(size_t)e * 4 + 1];
        float4 a2 = boo[(size_t)e * 4 + 2];
        float4 a3 = boo[(size_t)e * 4 + 3];
        float m0, m1, m2, m3;
        if (TRANS) {  // A^T v
            m0 = a0.x * v.x + a1.x * v.y + a2.x * v.z + a3.x * v.w;
            m1 = a0.y * v.x + a1.y * v.y + a2.y * v.z + a3.y * v.w;
            m2 = a0.z * v.x + a1.z * v.y + a2.z * v.z + a3.z * v.w;
            m3 = a0.w * v.x + a1.w * v.y + a2.w * v.z + a3.w * v.w;
        } else {      // A v
            m0 = a0.x * v.x + a0.y * v.y + a0.z * v.z + a0.w * v.w;
            m1 = a1.x * v.x + a1.y * v.y + a1.z * v.z + a1.w * v.w;
            m2 = a2.x * v.x + a2.y * v.y + a2.z * v.z + a2.w * v.w;
            m3 = a3.x * v.x + a3.y * v.y + a3.z * v.z + a3.w * v.w;
        }
        atomicAdd(&acc[0][loc], m0);
        atomicAdd(&acc[1][loc], m1);
        atomicAdd(&acc[2][loc], m2);
        atomicAdd(&acc[3][loc], m3);
    }
    __syncthreads();
    // merge partials: contiguous 16B per thread -> sector-merged atomics
    for (int i = tid; i < NPB; i += 512) {
        int node = b * NPB + i;
        if (node < N_NODES) {
            float* dst = vout + (size_t)node * 4;
            atomicAdd(dst + 0, acc[0][i]);
            atomicAdd(dst + 1, acc[1][i]);
            atomicAdd(dst + 2, acc[2][i]);
            atomicAdd(dst + 3, acc[3][i]);
        }
    }
}

// ================= fallback path (R3: sector-merged global atomics) =================

__global__ void __launch_bounds__(256) llt_pass1(
    const float* __restrict__ x, const int* __restrict__ row_idx,
    const int* __restrict__ col_idx, const float* __restrict__ boo,
    float* __restrict__ lt)
{
    int t = blockIdx.x * blockDim.x + threadIdx.x;
    if (t >= N_EDGES * 4) return;
    int e = t >> 2, i = t & 3;
    int r = row_idx[e], c = col_idx[e];
    const float* A = boo + (size_t)e * 16;
    const float* xv = x + (size_t)r * 4;
    float m = A[0*4+i]*xv[0] + A[1*4+i]*xv[1] + A[2*4+i]*xv[2] + A[3*4+i]*xv[3];
    atomicAdd(lt + (size_t)c * 4 + i, m);
}

__global__ void __launch_bounds__(256) llt_pass2(
    const float4* __restrict__ lt, const int* __restrict__ row_idx,
    const int* __restrict__ col_idx, const float4* __restrict__ boo,
    float* __restrict__ out)
{
    int t = blockIdx.x * blockDim.x + threadIdx.x;
    if (t >= N_EDGES * 4) return;
    int e = t >> 2, i = t & 3;
    int r = row_idx[e], c = col_idx[e];
    float4 arow = boo[(size_t)e * 4 + i];
    float4 lv = lt[c];
    float m = arow.x*lv.x + arow.y*lv.y + arow.z*lv.z + arow.w*lv.w;
    atomicAdd(out + (size_t)r * 4 + i, m);
}

// ================= host =================

extern "C" void kernel_launch(void* const* d_in, const int* in_sizes, int n_in,
                              void* d_out, int out_size, void* d_ws, size_t ws_size,
                              hipStream_t stream) {
    const float4* x = (const float4*)d_in[0];        // [100000,4] f32
    const int* edge_index = (const int*)d_in[1];     // [2, 3200000] int32
    const float4* boo = (const float4*)d_in[2];      // [3200000,4,4] f32
    const int* row = edge_index;                     // edge_index[0]
    const int* col = edge_index + N_EDGES;           // edge_index[1]
    float* out = (float*)d_out;

    auto align256 = [](size_t v) { return (v + 255) & ~(size_t)255; };
    const size_t sz_cm   = align256((size_t)NBK * WGC * 4);   // 1.6 MB each
    const size_t sz_vec  = align256((size_t)NBK * 4);
    const size_t sz_perm = align256((size_t)N_EDGES * 8);     // 25.6 MB (shared by passes)
    const size_t sz_lt   = align256((size_t)NBK * NPB * 16);  // 1.6 MB
    const size_t need = 2 * sz_cm + 4 * sz_vec + sz_perm + sz_lt;

    if (ws_size >= need) {
        char* p = (char*)d_ws;
        unsigned* cmC   = (unsigned*)p; p += sz_cm;
        unsigned* cmR   = (unsigned*)p; p += sz_cm;
        unsigned* totC  = (unsigned*)p; p += sz_vec;
        unsigned* totR  = (unsigned*)p; p += sz_vec;
        unsigned* baseC = (unsigned*)p; p += sz_vec;
        unsigned* baseR = (unsigned*)p; p += sz_vec;
        uint2*    perm  = (uint2*)p;    p += sz_perm;
        float*    lt    = (float*)p;    p += sz_lt;

        // zero accumulation targets (reduce merges partials atomically)
        hipMemsetAsync(lt, 0, (size_t)N_NODES * 4 * sizeof(float), stream);
        hipMemsetAsync(out, 0, (size_t)N_NODES * 4 * sizeof(float), stream);

        k_count<<<WGC, 256, 0, stream>>>(row, col, cmC, cmR);
        k_prefix<<<(2 * NBK + 3) / 4, 256, 0, stream>>>(cmC, cmR, totC, totR);
        k_scan<<<2, 256, 0, stream>>>(totC, totR, baseC, baseR);
        // pass 1: bucket by col, src = row, lt = A^T-scatter result
        k_partition<<<WGC, 256, 0, stream>>>(col, row, cmC, baseC, perm);
        k_reduce<1><<<NBK * PSPLIT, 512, 0, stream>>>(perm, x, boo, baseC, totC, lt);
        // pass 2: bucket by row, src = col (perm buffer reused)
        k_partition<<<WGC, 256, 0, stream>>>(row, col, cmR, baseR, perm);
        k_reduce<0><<<NBK * PSPLIT, 512, 0, stream>>>(perm, (const float4*)lt, boo, baseR, totR, out);
    } else {
        // fallback: sector-merged atomics (R3, 328 us)
        float* ltf = (float*)d_ws;
        hipMemsetAsync(ltf, 0, (size_t)N_NODES * 4 * sizeof(float), stream);
        hipMemsetAsync(out, 0, (size_t)N_NODES * 4 * sizeof(float), stream);
        const int grid = (N_EDGES * 4 + 255) / 256;
        llt_pass1<<<grid, 256, 0, stream>>>((const float*)x, row, col, (const float*)boo, ltf);
        llt_pass2<<<grid, 256, 0, stream>>>((const float4*)ltf, row, col, boo, out);
    }
}